// Round 6
// baseline (14065.022 us; speedup 1.0000x reference)
//
#include <hip/hip_runtime.h>

#define BATCH 128
#define SEQ   1024
#define INSZ  128
#define HID   256
#define NBLK  32
#define NTHR  512
#define FPB   8            // features per block
#define EPSV  1e-5f

typedef __attribute__((ext_vector_type(4))) float f32x4;
typedef __attribute__((ext_vector_type(8))) short short8;
typedef unsigned long long u64;
typedef unsigned u32;

__device__ __forceinline__ unsigned short f2bf(float f) {
  unsigned u = __builtin_bit_cast(unsigned, f);
  u += 0x7FFFu + ((u >> 16) & 1u);          // round-to-nearest-even
  return (unsigned short)(u >> 16);
}
__device__ __forceinline__ u64 cload64(const u32* p) {
  return __hip_atomic_load((const u64*)p, __ATOMIC_RELAXED, __HIP_MEMORY_SCOPE_AGENT);
}
__device__ __forceinline__ void cstore64(u32* p, u64 v) {
  __hip_atomic_store((u64*)p, v, __ATOMIC_RELAXED, __HIP_MEMORY_SCOPE_AGENT);
}
__device__ __forceinline__ short8 xcvt(float4 f0, float4 f1) {
  short8 v;
  v[0] = (short)f2bf(f0.x); v[1] = (short)f2bf(f0.y);
  v[2] = (short)f2bf(f0.z); v[3] = (short)f2bf(f0.w);
  v[4] = (short)f2bf(f1.x); v[5] = (short)f2bf(f1.y);
  v[6] = (short)f2bf(f1.z); v[7] = (short)f2bf(f1.w);
  return v;
}

__launch_bounds__(NTHR, 2)
__global__ void bnlstm_kernel(const float* __restrict__ x,
                              const float* __restrict__ W,
                              const float* __restrict__ gamma,
                              const float* __restrict__ beta,
                              float* __restrict__ out,
                              u32* __restrict__ hbuf) {   // [2][128][256] tagged (tag<<16)|bf16
  __shared__ float red1[2][8][32];                 // parity-buffered BN partials
  __shared__ float red2[2][8][32];
  __shared__ float waveTr[8][16][17];              // per-wave gate transpose
  __shared__ u32 hpack[8][16][8];                  // per-wave tagged h row-pack

  const int tid   = threadIdx.x;
  const int bid   = blockIdx.x;
  const int lane  = tid & 63;
  const int wid   = tid >> 6;                      // wave w owns batch rows 16w..16w+15
  const int col16 = lane & 15;
  const int kg    = lane >> 4;
  const int d     = col16 & 3;
  const int q     = col16 >> 2;
  const int arow  = wid * 16 + col16;              // A-frag row (batch index)
  const int brow  = wid * 16 + kg * 4 + d;         // gate/output row (batch index)

  // ---- B fragments in registers: 32 cols = (j_local 0..7) x (gate 0..3) ----
  short8 wf[2][12];
  for (int cg = 0; cg < 2; ++cg) {
    const int c32 = cg * 16 + col16;
    const int wcol = (c32 & 3) * HID + bid * FPB + (c32 >> 2);
    for (int kt = 0; kt < 12; ++kt) {
      short8 v;
      for (int e = 0; e < 8; ++e)
        v[e] = (short)f2bf(W[(kt * 32 + kg * 8 + e) * 1024 + wcol]);
      wf[cg][kt] = v;
    }
  }
  float gam = 0.f, bet = 0.f;
  if (lane < 32) {
    gam = gamma[(lane & 3) * HID + bid * FPB + (lane >> 2)];
    bet = beta [(lane & 3) * HID + bid * FPB + (lane >> 2)];
  }
  // bias input skipped: BN subtracts the batch mean, cancelling it exactly.

  float cst[2] = {0.f, 0.f};
  float hnv[2];

  // ---- x pipeline: xf = x(t) frags (ready); xn0..7 = x(t+1) loads in flight ----
  const float* xbase = x + (size_t)arow * (SEQ * INSZ) + kg * 8;
  short8 xf[4];
  #pragma unroll
  for (int kt = 0; kt < 4; ++kt)
    xf[kt] = xcvt(*(const float4*)(xbase + kt * 32),
                  *(const float4*)(xbase + kt * 32 + 4));
  float4 xn0, xn1, xn2, xn3, xn4, xn5, xn6, xn7;
  {
    const float* xr = xbase + INSZ;
    xn0 = *(const float4*)(xr);       xn1 = *(const float4*)(xr + 4);
    xn2 = *(const float4*)(xr + 32);  xn3 = *(const float4*)(xr + 36);
    xn4 = *(const float4*)(xr + 64);  xn5 = *(const float4*)(xr + 68);
    xn6 = *(const float4*)(xr + 96);  xn7 = *(const float4*)(xr + 100);
  }

  for (int t = 0; t < SEQ; ++t) {
    const int pR = t & 1;
    f32x4 acc0 = {0.f, 0.f, 0.f, 0.f}, acc1 = {0.f, 0.f, 0.f, 0.f};

    // ---- x-part MFMAs (frags ready since last step's bottom) ----
    #pragma unroll
    for (int kt = 0; kt < 4; ++kt) {
      acc0 = __builtin_amdgcn_mfma_f32_16x16x32_bf16(xf[kt], wf[0][kt], acc0, 0, 0, 0);
      acc1 = __builtin_amdgcn_mfma_f32_16x16x32_bf16(xf[kt], wf[1][kt], acc1, 0, 0, 0);
    }

    if (t > 0) {
      // ---- poll tagged h directly: data+tag in one dword, ONE visibility hop ----
      const u32* hb = hbuf + (size_t)pR * (BATCH * HID) + arow * HID + kg * 8;
      u64 hw[32];
      #pragma unroll
      for (int kt = 0; kt < 8; ++kt)
        #pragma unroll
        for (int u_ = 0; u_ < 4; ++u_)
          hw[kt * 4 + u_] = cload64(hb + kt * 32 + u_ * 2);
      const u64 exp2 = ((u64)(u32)t << 16) | ((u64)(u32)t << 48);
      while (true) {
        u64 bad = 0;
        #pragma unroll
        for (int i = 0; i < 32; ++i) bad |= (hw[i] ^ exp2) & 0xFFFF0000FFFF0000ULL;
        if (bad == 0) break;
        #pragma unroll
        for (int kt = 0; kt < 8; ++kt)
          #pragma unroll
          for (int u_ = 0; u_ < 4; ++u_)
            hw[kt * 4 + u_] = cload64(hb + kt * 32 + u_ * 2);
      }
      // ---- unpack (strip tags) + h-part MFMAs ----
      #pragma unroll
      for (int kt = 0; kt < 8; ++kt) {
        short8 af;
        u32* ad = (u32*)&af;
        #pragma unroll
        for (int u_ = 0; u_ < 4; ++u_) {
          u32 lo = (u32)hw[kt * 4 + u_];
          u32 hi = (u32)(hw[kt * 4 + u_] >> 32);
          ad[u_] = (lo & 0xFFFFu) | (hi << 16);
        }
        acc0 = __builtin_amdgcn_mfma_f32_16x16x32_bf16(af, wf[0][4 + kt], acc0, 0, 0, 0);
        acc1 = __builtin_amdgcn_mfma_f32_16x16x32_bf16(af, wf[1][4 + kt], acc1, 0, 0, 0);
      }
    }

    // ---- BN partials + the single intra-block barrier ----
    {
      float a1 = acc0[0] + acc0[1] + acc0[2] + acc0[3];
      float b1 = acc0[0]*acc0[0] + acc0[1]*acc0[1] + acc0[2]*acc0[2] + acc0[3]*acc0[3];
      float a2 = acc1[0] + acc1[1] + acc1[2] + acc1[3];
      float b2 = acc1[0]*acc1[0] + acc1[1]*acc1[1] + acc1[2]*acc1[2] + acc1[3]*acc1[3];
      a1 += __shfl_xor(a1, 16); b1 += __shfl_xor(b1, 16);
      a1 += __shfl_xor(a1, 32); b1 += __shfl_xor(b1, 32);
      a2 += __shfl_xor(a2, 16); b2 += __shfl_xor(b2, 16);
      a2 += __shfl_xor(a2, 32); b2 += __shfl_xor(b2, 32);
      if (lane < 16) {
        red1[pR][wid][lane] = a1;       red2[pR][wid][lane] = b1;
        red1[pR][wid][16 + lane] = a2;  red2[pR][wid][16 + lane] = b2;
      }
    }
    __syncthreads();

    // ---- BN finalize: redundant per wave (no second barrier) ----
    float sc0, sh0, sc1v, sh1v;
    {
      const int cidx = lane & 31;
      float S1 = 0.f, S2 = 0.f;
      #pragma unroll
      for (int w2 = 0; w2 < 8; ++w2) { S1 += red1[pR][w2][cidx]; S2 += red2[pR][w2][cidx]; }
      float mean = S1 * (1.f / BATCH);
      float var  = fmaxf(S2 * (1.f / BATCH) - mean * mean, 0.f);
      float scl = rsqrtf(var + EPSV) * gam;
      float shl = bet - mean * scl;
      sc0  = __shfl(scl, col16);       sh0  = __shfl(shl, col16);
      sc1v = __shfl(scl, 16 + col16);  sh1v = __shfl(shl, 16 + col16);
    }

    // ---- normalize + in-wave transpose + gates; pack tagged h ----
    #pragma unroll
    for (int cg = 0; cg < 2; ++cg) {
      f32x4 a = cg ? acc1 : acc0;
      const float sc = cg ? sc1v : sc0, sh = cg ? sh1v : sh0;
      #pragma unroll
      for (int i = 0; i < 4; ++i)
        waveTr[wid][kg * 4 + i][col16] = a[i] * sc + sh;
      float g0 = waveTr[wid][kg * 4 + d][q * 4 + 0];
      float g1 = waveTr[wid][kg * 4 + d][q * 4 + 1];
      float g2 = waveTr[wid][kg * 4 + d][q * 4 + 2];
      float g3 = waveTr[wid][kg * 4 + d][q * 4 + 3];
      float ig = 1.f / (1.f + __expf(-g0));
      float fg = 1.f / (1.f + __expf(-g1));
      float gg = 1.f - 2.f / (__expf(2.f * g2) + 1.f);
      float og = 1.f / (1.f + __expf(-g3));
      float cn = fg * cst[cg] + ig * gg;
      float hn = og * (1.f - 2.f / (__expf(2.f * cn) + 1.f));
      cst[cg] = cn;
      hnv[cg] = hn;
      hpack[wid][kg * 4 + d][cg * 4 + q] = ((u32)(t + 1) << 16) | (u32)f2bf(hn);
    }

    // ---- publish: fire-and-forget tagged stores, one u64 per lane ----
    if (t < SEQ - 1) {
      const int prow = lane >> 2, part = lane & 3;
      u64 v = *(const u64*)&hpack[wid][prow][part * 2];
      cstore64(hbuf + (size_t)(pR ^ 1) * (BATCH * HID)
               + (wid * 16 + prow) * HID + bid * FPB + part * 2, v);
      // no vmcnt drain, no flag: the tag travels with the data
    }

    // ---- off-critical-path: out stores, tail, x pipeline advance ----
    {
      float* po = &out[(size_t)brow * (SEQ * HID) + (size_t)t * HID + bid * FPB];
      po[q]     = hnv[0];
      po[4 + q] = hnv[1];
    }
    if (t == SEQ - 1) {
      float* ph = &out[(size_t)BATCH * SEQ * HID + (size_t)brow * HID + bid * FPB];
      ph[q] = hnv[0];                 ph[4 + q] = hnv[1];                // hy
      ph[BATCH * HID + q] = cst[0];   ph[BATCH * HID + 4 + q] = cst[1];  // cy
    } else {
      // convert x(t+1) (issued a full step ago -> landed) then issue x(t+2)
      xf[0] = xcvt(xn0, xn1); xf[1] = xcvt(xn2, xn3);
      xf[2] = xcvt(xn4, xn5); xf[3] = xcvt(xn6, xn7);
      if (t + 2 < SEQ) {
        const float* xr = xbase + (size_t)(t + 2) * INSZ;
        xn0 = *(const float4*)(xr);       xn1 = *(const float4*)(xr + 4);
        xn2 = *(const float4*)(xr + 32);  xn3 = *(const float4*)(xr + 36);
        xn4 = *(const float4*)(xr + 64);  xn5 = *(const float4*)(xr + 68);
        xn6 = *(const float4*)(xr + 96);  xn7 = *(const float4*)(xr + 100);
      }
    }
  }
}

extern "C" void kernel_launch(void* const* d_in, const int* in_sizes, int n_in,
                              void* d_out, int out_size, void* d_ws, size_t ws_size,
                              hipStream_t stream) {
  const float* x     = (const float*)d_in[0];
  const float* W     = (const float*)d_in[1];
  // d_in[2] = bias: cancelled by BatchNorm, unused.
  const float* gamma = (const float*)d_in[3];
  const float* beta  = (const float*)d_in[4];
  float* out = (float*)d_out;

  u32* hbuf = (u32*)d_ws;                          // 2 x 128 x 256 x 4B = 256 KB

  // zero tags each call: published tags are 1..1023, so 0 == "stale/empty"
  hipMemsetAsync(d_ws, 0, 2 * BATCH * HID * 4, stream);
  hipLaunchKernelGGL(bnlstm_kernel, dim3(NBLK), dim3(NTHR), 0, stream,
                     x, W, gamma, beta, out, hbuf);
}

// Round 8
// 7753.503 us; speedup vs baseline: 1.8140x; 1.8140x over previous
//
#include <hip/hip_runtime.h>

#define BATCH 128
#define SEQ   1024
#define INSZ  128
#define HID   256
#define NBLK  32
#define NTHR  512
#define FPB   8            // features per block
#define EPSV  1e-5f

typedef __attribute__((ext_vector_type(4))) float f32x4;
typedef __attribute__((ext_vector_type(8))) short short8;
typedef unsigned long long u64;
typedef unsigned u32;

__device__ __forceinline__ unsigned short f2bf(float f) {
  unsigned u = __builtin_bit_cast(unsigned, f);
  u += 0x7FFFu + ((u >> 16) & 1u);          // round-to-nearest-even
  return (unsigned short)(u >> 16);
}
// ONLY proven coherence primitives (R2-R6): compiler-generated agent-scope ops.
__device__ __forceinline__ u64 cload64(const unsigned short* p) {
  return __hip_atomic_load((const u64*)p, __ATOMIC_RELAXED, __HIP_MEMORY_SCOPE_AGENT);
}
__device__ __forceinline__ void cstore64(unsigned short* p, u64 v) {
  __hip_atomic_store((u64*)p, v, __ATOMIC_RELAXED, __HIP_MEMORY_SCOPE_AGENT);
}
__device__ __forceinline__ short8 xcvt(float4 f0, float4 f1) {
  short8 v;
  v[0] = (short)f2bf(f0.x); v[1] = (short)f2bf(f0.y);
  v[2] = (short)f2bf(f0.z); v[3] = (short)f2bf(f0.w);
  v[4] = (short)f2bf(f1.x); v[5] = (short)f2bf(f1.y);
  v[6] = (short)f2bf(f1.z); v[7] = (short)f2bf(f1.w);
  return v;
}

__launch_bounds__(NTHR)
__global__ void bnlstm_kernel(const float* __restrict__ x,
                              const float* __restrict__ W,
                              const float* __restrict__ gamma,
                              const float* __restrict__ beta,
                              float* __restrict__ out,
                              unsigned short* __restrict__ hbuf,   // [2][128][256] bf16
                              u32* __restrict__ flags) {           // [32] PACKED (one line)
  __shared__ float red1[2][8][32];                 // parity-buffered BN partials
  __shared__ float red2[2][8][32];
  __shared__ float waveTr[8][16][17];              // per-wave gate transpose
  __shared__ unsigned short hpack[8][16][8];       // per-wave h row-pack

  const int tid   = threadIdx.x;
  const int bid   = blockIdx.x;
  const int lane  = tid & 63;
  const int wid   = tid >> 6;                      // wave w owns batch rows 16w..16w+15
  const int col16 = lane & 15;
  const int kg    = lane >> 4;
  const int d     = col16 & 3;
  const int q     = col16 >> 2;
  const int arow  = wid * 16 + col16;              // A-frag row (batch index)
  const int brow  = wid * 16 + kg * 4 + d;         // gate/output row (batch index)

  // ---- B fragments in registers: 32 cols = (j_local 0..7) x (gate 0..3) ----
  short8 wf[2][12];
  for (int cg = 0; cg < 2; ++cg) {
    const int c32 = cg * 16 + col16;
    const int wcol = (c32 & 3) * HID + bid * FPB + (c32 >> 2);
    for (int kt = 0; kt < 12; ++kt) {
      short8 v;
      for (int e = 0; e < 8; ++e)
        v[e] = (short)f2bf(W[(kt * 32 + kg * 8 + e) * 1024 + wcol]);
      wf[cg][kt] = v;
    }
  }
  float gam = 0.f, bet = 0.f;
  if (lane < 32) {
    gam = gamma[(lane & 3) * HID + bid * FPB + (lane >> 2)];
    bet = beta [(lane & 3) * HID + bid * FPB + (lane >> 2)];
  }
  // bias input skipped: BN subtracts the batch mean, cancelling it exactly.

  float cst[2] = {0.f, 0.f};
  float hnv[2];

  // x(t) f32 loads in flight; converted at the top of step t (const-index arrays only)
  const float* xbase = x + (size_t)arow * (SEQ * INSZ) + kg * 8;
  float4 xv[8];
  #pragma unroll
  for (int kt = 0; kt < 4; ++kt) {
    xv[2 * kt]     = *(const float4*)(xbase + kt * 32);
    xv[2 * kt + 1] = *(const float4*)(xbase + kt * 32 + 4);
  }

  for (int t = 0; t < SEQ; ++t) {
    const int pR = t & 1;
    f32x4 acc0 = {0.f, 0.f, 0.f, 0.f}, acc1 = {0.f, 0.f, 0.f, 0.f};

    // ---- convert + x-part MFMAs: fills the producer-wait with useful work ----
    #pragma unroll
    for (int kt = 0; kt < 4; ++kt) {
      short8 ax = xcvt(xv[2 * kt], xv[2 * kt + 1]);
      acc0 = __builtin_amdgcn_mfma_f32_16x16x32_bf16(ax, wf[0][kt], acc0, 0, 0, 0);
      acc1 = __builtin_amdgcn_mfma_f32_16x16x32_bf16(ax, wf[1][kt], acc1, 0, 0, 0);
    }

    if (t > 0) {
      // ---- detect: ONLY wave 0 polls the single packed flag line ----
      if (wid == 0) {
        const u32 tv = (u32)t;
        while (true) {
          u32 v = (lane < NBLK)
            ? __hip_atomic_load(&flags[lane], __ATOMIC_RELAXED, __HIP_MEMORY_SCOPE_AGENT)
            : tv;
          if (__all((int)(v >= tv))) break;
          __builtin_amdgcn_s_sleep(4);
        }
      }
      __syncthreads();          // release: waves 1-7 waited here (zero IC traffic)

      // ---- h: IC -> registers as A-frags, ONE bulk pass, no retries ----
      const unsigned short* hb = hbuf + pR * (BATCH * HID) + arow * HID + kg * 8;
      u64 hv[16];
      #pragma unroll
      for (int kt = 0; kt < 8; ++kt) {
        hv[2 * kt]     = cload64(hb + kt * 32);
        hv[2 * kt + 1] = cload64(hb + kt * 32 + 4);
      }
      #pragma unroll
      for (int kt = 0; kt < 8; ++kt) {
        short8 af;
        *(u64*)&af       = hv[2 * kt];
        *((u64*)&af + 1) = hv[2 * kt + 1];
        acc0 = __builtin_amdgcn_mfma_f32_16x16x32_bf16(af, wf[0][4 + kt], acc0, 0, 0, 0);
        acc1 = __builtin_amdgcn_mfma_f32_16x16x32_bf16(af, wf[1][4 + kt], acc1, 0, 0, 0);
      }
    }

    // ---- BN partials + intra-block barrier (no loads outstanding here) ----
    {
      float a1 = acc0[0] + acc0[1] + acc0[2] + acc0[3];
      float b1 = acc0[0]*acc0[0] + acc0[1]*acc0[1] + acc0[2]*acc0[2] + acc0[3]*acc0[3];
      float a2 = acc1[0] + acc1[1] + acc1[2] + acc1[3];
      float b2 = acc1[0]*acc1[0] + acc1[1]*acc1[1] + acc1[2]*acc1[2] + acc1[3]*acc1[3];
      a1 += __shfl_xor(a1, 16); b1 += __shfl_xor(b1, 16);
      a1 += __shfl_xor(a1, 32); b1 += __shfl_xor(b1, 32);
      a2 += __shfl_xor(a2, 16); b2 += __shfl_xor(b2, 16);
      a2 += __shfl_xor(a2, 32); b2 += __shfl_xor(b2, 32);
      if (lane < 16) {
        red1[pR][wid][lane] = a1;       red2[pR][wid][lane] = b1;
        red1[pR][wid][16 + lane] = a2;  red2[pR][wid][16 + lane] = b2;
      }
    }
    __syncthreads();

    // ---- BN finalize: redundant per wave (parity-buffered partials) ----
    float sc0v, sh0v, sc1v, sh1v;
    {
      const int cidx = lane & 31;
      float S1 = 0.f, S2 = 0.f;
      #pragma unroll
      for (int w2 = 0; w2 < 8; ++w2) { S1 += red1[pR][w2][cidx]; S2 += red2[pR][w2][cidx]; }
      float mean = S1 * (1.f / BATCH);
      float var  = fmaxf(S2 * (1.f / BATCH) - mean * mean, 0.f);
      float scl = rsqrtf(var + EPSV) * gam;
      float shl = bet - mean * scl;
      sc0v = __shfl(scl, col16);       sh0v = __shfl(shl, col16);
      sc1v = __shfl(scl, 16 + col16);  sh1v = __shfl(shl, 16 + col16);
    }

    // ---- normalize + in-wave transpose + gates ----
    #pragma unroll
    for (int cg = 0; cg < 2; ++cg) {
      f32x4 a = cg ? acc1 : acc0;
      const float sc = cg ? sc1v : sc0v, sh = cg ? sh1v : sh0v;
      #pragma unroll
      for (int i = 0; i < 4; ++i)
        waveTr[wid][kg * 4 + i][col16] = a[i] * sc + sh;
      float g0 = waveTr[wid][kg * 4 + d][q * 4 + 0];
      float g1 = waveTr[wid][kg * 4 + d][q * 4 + 1];
      float g2 = waveTr[wid][kg * 4 + d][q * 4 + 2];
      float g3 = waveTr[wid][kg * 4 + d][q * 4 + 3];
      float ig = 1.f / (1.f + __expf(-g0));
      float fg = 1.f / (1.f + __expf(-g1));
      float gg = 1.f - 2.f / (__expf(2.f * g2) + 1.f);
      float og = 1.f / (1.f + __expf(-g3));
      float cn = fg * cst[cg] + ig * gg;
      float hn = og * (1.f - 2.f / (__expf(2.f * cn) + 1.f));
      cst[cg] = cn;
      hnv[cg] = hn;
      hpack[wid][kg * 4 + d][cg * 4 + q] = f2bf(hn);
    }

    // ---- publish: h stores -> barrier (implicit per-wave vmcnt(0) proves acks)
    // ---- -> tid0 raises this block's flag (single-writer dword, no RMW) ----
    if (t < SEQ - 1) {
      if (lane < 16) {
        const u64* hp = (const u64*)&hpack[wid][lane][0];
        u64 v0 = hp[0], v1 = hp[1];
        unsigned short* hd = hbuf + (pR ^ 1) * (BATCH * HID)
                           + (wid * 16 + lane) * HID + bid * FPB;
        cstore64(hd, v0);
        cstore64(hd + 4, v1);
      }
      __syncthreads();          // drains every wave's h stores before the flag
      if (tid == 0)
        __hip_atomic_store(&flags[bid], (u32)(t + 1),
                           __ATOMIC_RELAXED, __HIP_MEMORY_SCOPE_AGENT);
    }

    // ---- off-critical-path: out stores, tail, x(t+1) issue (convert next top) ----
    {
      float* po = &out[(size_t)brow * (SEQ * HID) + (size_t)t * HID + bid * FPB];
      po[q]     = hnv[0];
      po[4 + q] = hnv[1];
    }
    if (t == SEQ - 1) {
      float* ph = &out[(size_t)BATCH * SEQ * HID + (size_t)brow * HID + bid * FPB];
      ph[q] = hnv[0];                 ph[4 + q] = hnv[1];                // hy
      ph[BATCH * HID + q] = cst[0];   ph[BATCH * HID + 4 + q] = cst[1];  // cy
    } else {
      const float* xr = xbase + (size_t)(t + 1) * INSZ;
      #pragma unroll
      for (int kt = 0; kt < 4; ++kt) {
        xv[2 * kt]     = *(const float4*)(xr + kt * 32);
        xv[2 * kt + 1] = *(const float4*)(xr + kt * 32 + 4);
      }
    }
  }
}

extern "C" void kernel_launch(void* const* d_in, const int* in_sizes, int n_in,
                              void* d_out, int out_size, void* d_ws, size_t ws_size,
                              hipStream_t stream) {
  const float* x     = (const float*)d_in[0];
  const float* W     = (const float*)d_in[1];
  // d_in[2] = bias: cancelled by BatchNorm, unused.
  const float* gamma = (const float*)d_in[3];
  const float* beta  = (const float*)d_in[4];
  float* out = (float*)d_out;

  u32* flags = (u32*)d_ws;                                         // 32 dwords, ONE line
  unsigned short* hbuf = (unsigned short*)((char*)d_ws + 4096);    // 2 x 64 KB

  // reset flags each call (t=0 skips the h read, so hbuf needs no init)
  hipMemsetAsync(d_ws, 0, 4096, stream);
  hipLaunchKernelGGL(bnlstm_kernel, dim3(NBLK), dim3(NTHR), 0, stream,
                     x, W, gamma, beta, out, hbuf, flags);
}